// Round 1
// baseline (797.462 us; speedup 1.0000x reference)
//
#include <hip/hip_runtime.h>
#include <hip/hip_bf16.h>

#define DEVI __device__ __forceinline__

typedef short bf16x8 __attribute__((ext_vector_type(8)));
typedef float f32x4  __attribute__((ext_vector_type(4)));

// Problem constants (B=32, H=W=56, C=256, wh=ww=7, shift=3, heads=8, hd=32)
constexpr int MROWS = 100352;            // 32 * 64 * 49 window-order rows
constexpr int BM = 128, BN = 128, BK = 64;

// window-order row -> flat token index (b*3136 + h*56 + w).
// Same map serves LN1 gather (read source of window row) and proj scatter
// (destination after window-reverse + roll(+3,+3)).
DEVI int win_row_to_token(int r) {
  int b   = r / 3136;
  int rem = r - b * 3136;
  int wi  = rem / 49;
  int t   = rem - wi * 49;
  int nwh = wi >> 3, nww = wi & 7;
  int th = t / 7, tw = t - th * 7;
  int h = nwh * 7 + th + 3; if (h >= 56) h -= 56;
  int w = nww * 7 + tw + 3; if (w >= 56) w -= 56;
  return b * 3136 + h * 56 + w;
}

DEVI unsigned short f2bf(float f) {
  __hip_bfloat16 h = __float2bfloat16(f);
  return __builtin_bit_cast(unsigned short, h);
}

// ---------------- fp32 -> bf16 weight convert ----------------
__global__ void cvt_kernel(const float* __restrict__ in, __hip_bfloat16* __restrict__ out, int n) {
  int i = blockIdx.x * 256 + threadIdx.x;
  if (i < n) out[i] = __float2bfloat16(in[i]);
}

// ---------------- LayerNorm (one wave per token row, C=256) ----------------
// WIN=true : output row r is window-order, source token = map(r)  (LN1)
// WIN=false: straight rows (LN2)
template<bool WIN>
__global__ __launch_bounds__(256) void ln_kernel(
    const float* __restrict__ xin, const float* __restrict__ g,
    const float* __restrict__ b, __hip_bfloat16* __restrict__ outb)
{
  int r = blockIdx.x * 4 + (threadIdx.x >> 6);
  int l = threadIdx.x & 63;
  int tok = WIN ? win_row_to_token(r) : r;
  float4 xv = *(const float4*)&xin[(size_t)tok * 256 + l * 4];
  float s = xv.x + xv.y + xv.z + xv.w;
  float q = xv.x * xv.x + xv.y * xv.y + xv.z * xv.z + xv.w * xv.w;
  #pragma unroll
  for (int off = 32; off; off >>= 1) { s += __shfl_xor(s, off); q += __shfl_xor(q, off); }
  float mu = s * (1.0f / 256.0f);
  float var = q * (1.0f / 256.0f) - mu * mu;
  float rs = rsqrtf(var + 1e-5f);
  float4 gv = *(const float4*)&g[l * 4];
  float4 bv = *(const float4*)&b[l * 4];
  ushort4 st;
  st.x = f2bf((xv.x - mu) * rs * gv.x + bv.x);
  st.y = f2bf((xv.y - mu) * rs * gv.y + bv.y);
  st.z = f2bf((xv.z - mu) * rs * gv.z + bv.z);
  st.w = f2bf((xv.w - mu) * rs * gv.w + bv.w);
  *(ushort4*)&outb[(size_t)r * 256 + l * 4] = st;
}

// ---------------- bf16 MFMA GEMM: out(M,N) = A(M,K) * Bw(N,K)^T ----------------
// 128x128 tile, 4 waves (2x2), each wave 64x64 = 4x4 frags of 16x16x32.
enum { EPI_QKV = 0, EPI_PROJ = 1, EPI_MLP1 = 2, EPI_MLP2 = 3 };

template<int EPI>
__global__ __launch_bounds__(256) void gemm_kernel(
    const __hip_bfloat16* __restrict__ A,
    const __hip_bfloat16* __restrict__ Bw,
    int N, int K,
    const float* __restrict__ bias,
    const float* __restrict__ xres,   // PROJ: original x (token order)
    float* __restrict__ outf,         // PROJ/MLP2: d_out
    __hip_bfloat16* __restrict__ outb)// QKV/MLP1
{
  __shared__ __align__(16) __hip_bfloat16 lsA[BM * BK];
  __shared__ __align__(16) __hip_bfloat16 lsB[BN * BK];
  const int ntiles = N / BN;
  int mt = blockIdx.x / ntiles;
  int nt = blockIdx.x - mt * ntiles;
  const int w = threadIdx.x >> 6, l = threadIdx.x & 63;
  const int wr = (w >> 1) * 64, wc = (w & 1) * 64;
  f32x4 acc[4][4] = {};
  const __hip_bfloat16* Abase = A  + (size_t)mt * BM * K;
  const __hip_bfloat16* Bbase = Bw + (size_t)nt * BN * K;
  const int srow = l >> 3;          // row within 8-row chunk
  const int skb  = (l & 7) * 8;     // bf16 offset within row (16B granules)

  for (int kt = 0; kt < K; kt += BK) {
    #pragma unroll
    for (int i = 0; i < 4; ++i) {
      int chunk = w * 4 + i;        // 0..15, each = 8 rows x 64 bf16 = 1KB
      int row = chunk * 8 + srow;
      __builtin_amdgcn_global_load_lds(
          (const __attribute__((address_space(1))) void*)(Abase + (size_t)row * K + kt + skb),
          (__attribute__((address_space(3))) void*)(&lsA[chunk * 512]), 16, 0, 0);
      __builtin_amdgcn_global_load_lds(
          (const __attribute__((address_space(1))) void*)(Bbase + (size_t)row * K + kt + skb),
          (__attribute__((address_space(3))) void*)(&lsB[chunk * 512]), 16, 0, 0);
    }
    __syncthreads();
    #pragma unroll
    for (int kk = 0; kk < 2; ++kk) {
      bf16x8 af[4], bfr[4];
      #pragma unroll
      for (int mi = 0; mi < 4; ++mi)
        af[mi] = *(const bf16x8*)&lsA[(wr + mi * 16 + (l & 15)) * 64 + kk * 32 + (l >> 4) * 8];
      #pragma unroll
      for (int ni = 0; ni < 4; ++ni)
        bfr[ni] = *(const bf16x8*)&lsB[(wc + ni * 16 + (l & 15)) * 64 + kk * 32 + (l >> 4) * 8];
      #pragma unroll
      for (int mi = 0; mi < 4; ++mi)
        #pragma unroll
        for (int ni = 0; ni < 4; ++ni)
          acc[mi][ni] = __builtin_amdgcn_mfma_f32_16x16x32_bf16(af[mi], bfr[ni], acc[mi][ni], 0, 0, 0);
    }
    __syncthreads();
  }

  const int lcol = l & 15, lrow4 = (l >> 4) * 4;
  #pragma unroll
  for (int mi = 0; mi < 4; ++mi) {
    #pragma unroll
    for (int j = 0; j < 4; ++j) {
      int grow = mt * BM + wr + mi * 16 + lrow4 + j;
      int orow = grow;
      if (EPI == EPI_PROJ) orow = win_row_to_token(grow);
      #pragma unroll
      for (int ni = 0; ni < 4; ++ni) {
        int gcol = nt * BN + wc + ni * 16 + lcol;
        float v = acc[mi][ni][j] + bias[gcol];
        if (EPI == EPI_QKV) {
          outb[(size_t)grow * 768 + gcol] = __float2bfloat16(v);
        } else if (EPI == EPI_PROJ) {
          size_t o = (size_t)orow * 256 + gcol;
          outf[o] = xres[o] + v;                       // residual 1
        } else if (EPI == EPI_MLP1) {
          float ge = 0.5f * v * (1.0f + erff(v * 0.70710678118654752f));
          outb[(size_t)grow * 1024 + gcol] = __float2bfloat16(ge);
        } else { // MLP2
          size_t o = (size_t)grow * 256 + gcol;
          outf[o] += v;                                // residual 2 (in-place)
        }
      }
    }
  }
}

// ---------------- attention: one block per (window, head) ----------------
__global__ __launch_bounds__(256) void attn_kernel(
    const __hip_bfloat16* __restrict__ qkv,
    const float* __restrict__ bias_table,
    __hip_bfloat16* __restrict__ attn_out)
{
  int blk = blockIdx.x;
  int win = blk >> 3, h = blk & 7;
  int wi_img = win & 63;
  int nwh = wi_img >> 3, nww = wi_img & 7;

  __shared__ float Qs[49][33], Ks[49][33], Vs[49][33];
  __shared__ float S[49 * 49];
  __shared__ float linv[49];
  __shared__ int   regs_s[49];
  int tid = threadIdx.x;
  const float scale = 0.17677669529663687f;  // 1/sqrt(32)

  size_t base = (size_t)win * 49 * 768 + h * 32;
  for (int idx = tid; idx < 49 * 32; idx += 256) {
    int i = idx >> 5, d = idx & 31;
    size_t o = base + (size_t)i * 768 + d;
    Qs[i][d] = __bfloat162float(qkv[o]) * scale;
    Ks[i][d] = __bfloat162float(qkv[o + 256]);
    Vs[i][d] = __bfloat162float(qkv[o + 512]);
  }
  if (tid < 49) {
    int th = tid / 7, tw = tid - th * 7;
    int gh = nwh * 7 + th, gw = nww * 7 + tw;
    int rh = (gh < 49) ? 0 : ((gh < 53) ? 1 : 2);
    int rw = (gw < 49) ? 0 : ((gw < 53) ? 1 : 2);
    regs_s[tid] = rh * 3 + rw;
  }
  __syncthreads();

  for (int e = tid; e < 49 * 49; e += 256) {
    int i = e / 49, j = e - i * 49;
    float a = 0.0f;
    #pragma unroll
    for (int d = 0; d < 32; ++d) a += Qs[i][d] * Ks[j][d];
    int ih = i / 7, iw = i - ih * 7;
    int jh = j / 7, jw = j - jh * 7;
    int rpi = (ih - jh + 6) * 13 + (iw - jw + 6);
    a += bias_table[rpi * 8 + h];
    if (regs_s[i] != regs_s[j]) a -= 100.0f;
    S[e] = a;
  }
  __syncthreads();

  if (tid < 49) {
    float m = -1e30f;
    for (int j = 0; j < 49; ++j) m = fmaxf(m, S[tid * 49 + j]);
    float s = 0.0f;
    for (int j = 0; j < 49; ++j) {
      float e = __expf(S[tid * 49 + j] - m);
      S[tid * 49 + j] = e;
      s += e;
    }
    linv[tid] = 1.0f / s;
  }
  __syncthreads();

  for (int idx = tid; idx < 49 * 32; idx += 256) {
    int i = idx >> 5, d = idx & 31;
    float a = 0.0f;
    #pragma unroll
    for (int j = 0; j < 49; ++j) a += S[i * 49 + j] * Vs[j][d];
    attn_out[(size_t)(win * 49 + i) * 256 + h * 32 + d] = __float2bfloat16(a * linv[i]);
  }
}

// ---------------- host launch ----------------
extern "C" void kernel_launch(void* const* d_in, const int* in_sizes, int n_in,
                              void* d_out, int out_size, void* d_ws, size_t ws_size,
                              hipStream_t stream) {
  const float* x          = (const float*)d_in[0];
  const float* g1         = (const float*)d_in[1];
  const float* b1         = (const float*)d_in[2];
  const float* qkv_w      = (const float*)d_in[3];
  const float* qkv_b      = (const float*)d_in[4];
  const float* bias_table = (const float*)d_in[5];
  const float* proj_w     = (const float*)d_in[6];
  const float* proj_b     = (const float*)d_in[7];
  const float* g2         = (const float*)d_in[8];
  const float* b2         = (const float*)d_in[9];
  const float* w1         = (const float*)d_in[10];
  const float* bm1        = (const float*)d_in[11];
  const float* w2         = (const float*)d_in[12];
  const float* bm2        = (const float*)d_in[13];
  float* out = (float*)d_out;

  char* ws = (char*)d_ws;
  // layout (bytes):
  //   A_ln   @ 0          : 100352*256*2  = 51,380,224   (LN1 out, windowed; later LN2 out)
  //   qkv    @ 51380224   : 100352*768*2  = 154,140,672
  //   attn_o @ 205520896  : 100352*256*2  = 51,380,224
  //   weights@ 256901120  : 786432*2      = 1,572,864
  // MLP hidden (100352*1024*2 = 205,520,896) reuses [qkv .. attn_o] exactly.
  __hip_bfloat16* A_ln   = (__hip_bfloat16*)(ws);
  __hip_bfloat16* qkvb   = (__hip_bfloat16*)(ws + 51380224);
  __hip_bfloat16* attn_o = (__hip_bfloat16*)(ws + 205520896);
  __hip_bfloat16* hidden = qkvb;
  __hip_bfloat16* qkv_wb  = (__hip_bfloat16*)(ws + 256901120);
  __hip_bfloat16* proj_wb = qkv_wb + 196608;
  __hip_bfloat16* w1b     = proj_wb + 65536;
  __hip_bfloat16* w2b     = w1b + 262144;

  cvt_kernel<<<(196608 + 255) / 256, 256, 0, stream>>>(qkv_w, qkv_wb, 196608);
  cvt_kernel<<<(65536  + 255) / 256, 256, 0, stream>>>(proj_w, proj_wb, 65536);
  cvt_kernel<<<(262144 + 255) / 256, 256, 0, stream>>>(w1, w1b, 262144);
  cvt_kernel<<<(262144 + 255) / 256, 256, 0, stream>>>(w2, w2b, 262144);

  ln_kernel<true><<<MROWS / 4, 256, 0, stream>>>(x, g1, b1, A_ln);

  gemm_kernel<EPI_QKV><<<(MROWS / BM) * (768 / BN), 256, 0, stream>>>(
      A_ln, qkv_wb, 768, 256, qkv_b, nullptr, nullptr, qkvb);

  attn_kernel<<<2048 * 8, 256, 0, stream>>>(qkvb, bias_table, attn_o);

  gemm_kernel<EPI_PROJ><<<(MROWS / BM) * (256 / BN), 256, 0, stream>>>(
      attn_o, proj_wb, 256, 256, proj_b, x, out, nullptr);

  ln_kernel<false><<<MROWS / 4, 256, 0, stream>>>(out, g2, b2, A_ln);

  gemm_kernel<EPI_MLP1><<<(MROWS / BM) * (1024 / BN), 256, 0, stream>>>(
      A_ln, w1b, 1024, 256, bm1, nullptr, nullptr, hidden);

  gemm_kernel<EPI_MLP2><<<(MROWS / BM) * (256 / BN), 256, 0, stream>>>(
      hidden, w2b, 256, 1024, bm2, nullptr, out, nullptr);
}

// Round 2
// 560.751 us; speedup vs baseline: 1.4221x; 1.4221x over previous
//
#include <hip/hip_runtime.h>
#include <hip/hip_bf16.h>

#define DEVI __device__ __forceinline__

typedef short bf16x8 __attribute__((ext_vector_type(8)));
typedef float f32x4  __attribute__((ext_vector_type(4)));

// Problem constants (B=32, H=W=56, C=256, wh=ww=7, shift=3, heads=8, hd=32)
constexpr int MROWS = 100352;            // 32 * 64 * 49 window-order rows
constexpr int BM = 128, BN = 128, BK = 64;

// window-order row -> flat token index (b*3136 + h*56 + w).
DEVI int win_row_to_token(int r) {
  int b   = r / 3136;
  int rem = r - b * 3136;
  int wi  = rem / 49;
  int t   = rem - wi * 49;
  int nwh = wi >> 3, nww = wi & 7;
  int th = t / 7, tw = t - th * 7;
  int h = nwh * 7 + th + 3; if (h >= 56) h -= 56;
  int w = nww * 7 + tw + 3; if (w >= 56) w -= 56;
  return b * 3136 + h * 56 + w;
}

DEVI unsigned short f2bf(float f) {
  __hip_bfloat16 h = __float2bfloat16(f);
  return __builtin_bit_cast(unsigned short, h);
}

// ---------------- fp32 -> bf16 weight convert ----------------
__global__ void cvt_kernel(const float* __restrict__ in, __hip_bfloat16* __restrict__ out, int n) {
  int i = blockIdx.x * 256 + threadIdx.x;
  if (i < n) out[i] = __float2bfloat16(in[i]);
}

// ---------------- LayerNorm (one wave per token row, C=256) ----------------
template<bool WIN>
__global__ __launch_bounds__(256) void ln_kernel(
    const float* __restrict__ xin, const float* __restrict__ g,
    const float* __restrict__ b, __hip_bfloat16* __restrict__ outb)
{
  int r = blockIdx.x * 4 + (threadIdx.x >> 6);
  int l = threadIdx.x & 63;
  int tok = WIN ? win_row_to_token(r) : r;
  float4 xv = *(const float4*)&xin[(size_t)tok * 256 + l * 4];
  float s = xv.x + xv.y + xv.z + xv.w;
  float q = xv.x * xv.x + xv.y * xv.y + xv.z * xv.z + xv.w * xv.w;
  #pragma unroll
  for (int off = 32; off; off >>= 1) { s += __shfl_xor(s, off); q += __shfl_xor(q, off); }
  float mu = s * (1.0f / 256.0f);
  float var = q * (1.0f / 256.0f) - mu * mu;
  float rs = rsqrtf(var + 1e-5f);
  float4 gv = *(const float4*)&g[l * 4];
  float4 bv = *(const float4*)&b[l * 4];
  ushort4 st;
  st.x = f2bf((xv.x - mu) * rs * gv.x + bv.x);
  st.y = f2bf((xv.y - mu) * rs * gv.y + bv.y);
  st.z = f2bf((xv.z - mu) * rs * gv.z + bv.z);
  st.w = f2bf((xv.w - mu) * rs * gv.w + bv.w);
  *(ushort4*)&outb[(size_t)r * 256 + l * 4] = st;
}

// ---------------- bf16 MFMA GEMM: out(M,N) = A(M,K) * Bw(N,K)^T ----------------
enum { EPI_QKV = 0, EPI_PROJ = 1, EPI_MLP1 = 2, EPI_MLP2 = 3 };

template<int EPI>
__global__ __launch_bounds__(256) void gemm_kernel(
    const __hip_bfloat16* __restrict__ A,
    const __hip_bfloat16* __restrict__ Bw,
    int N, int K,
    const float* __restrict__ bias,
    const float* __restrict__ xres,   // PROJ: original x (token order)
    float* __restrict__ outf,         // PROJ/MLP2: d_out
    __hip_bfloat16* __restrict__ outb)// QKV/MLP1
{
  __shared__ __align__(16) __hip_bfloat16 lsA[BM * BK];
  __shared__ __align__(16) __hip_bfloat16 lsB[BN * BK];
  const int ntiles = N / BN;
  int mt = blockIdx.x / ntiles;
  int nt = blockIdx.x - mt * ntiles;
  const int w = threadIdx.x >> 6, l = threadIdx.x & 63;
  const int wr = (w >> 1) * 64, wc = (w & 1) * 64;
  f32x4 acc[4][4] = {};
  const __hip_bfloat16* Abase = A  + (size_t)mt * BM * K;
  const __hip_bfloat16* Bbase = Bw + (size_t)nt * BN * K;
  const int srow = l >> 3;
  const int skb  = (l & 7) * 8;

  for (int kt = 0; kt < K; kt += BK) {
    #pragma unroll
    for (int i = 0; i < 4; ++i) {
      int chunk = w * 4 + i;
      int row = chunk * 8 + srow;
      __builtin_amdgcn_global_load_lds(
          (const __attribute__((address_space(1))) void*)(Abase + (size_t)row * K + kt + skb),
          (__attribute__((address_space(3))) void*)(&lsA[chunk * 512]), 16, 0, 0);
      __builtin_amdgcn_global_load_lds(
          (const __attribute__((address_space(1))) void*)(Bbase + (size_t)row * K + kt + skb),
          (__attribute__((address_space(3))) void*)(&lsB[chunk * 512]), 16, 0, 0);
    }
    __syncthreads();
    #pragma unroll
    for (int kk = 0; kk < 2; ++kk) {
      bf16x8 af[4], bfr[4];
      #pragma unroll
      for (int mi = 0; mi < 4; ++mi)
        af[mi] = *(const bf16x8*)&lsA[(wr + mi * 16 + (l & 15)) * 64 + kk * 32 + (l >> 4) * 8];
      #pragma unroll
      for (int ni = 0; ni < 4; ++ni)
        bfr[ni] = *(const bf16x8*)&lsB[(wc + ni * 16 + (l & 15)) * 64 + kk * 32 + (l >> 4) * 8];
      #pragma unroll
      for (int mi = 0; mi < 4; ++mi)
        #pragma unroll
        for (int ni = 0; ni < 4; ++ni)
          acc[mi][ni] = __builtin_amdgcn_mfma_f32_16x16x32_bf16(af[mi], bfr[ni], acc[mi][ni], 0, 0, 0);
    }
    __syncthreads();
  }

  const int lcol = l & 15, lrow4 = (l >> 4) * 4;
  #pragma unroll
  for (int mi = 0; mi < 4; ++mi) {
    #pragma unroll
    for (int j = 0; j < 4; ++j) {
      int grow = mt * BM + wr + mi * 16 + lrow4 + j;
      int orow = grow;
      if (EPI == EPI_PROJ) orow = win_row_to_token(grow);
      #pragma unroll
      for (int ni = 0; ni < 4; ++ni) {
        int gcol = nt * BN + wc + ni * 16 + lcol;
        float v = acc[mi][ni][j] + bias[gcol];
        if (EPI == EPI_QKV) {
          outb[(size_t)grow * 768 + gcol] = __float2bfloat16(v);
        } else if (EPI == EPI_PROJ) {
          size_t o = (size_t)orow * 256 + gcol;
          outf[o] = xres[o] + v;
        } else if (EPI == EPI_MLP1) {
          float ge = 0.5f * v * (1.0f + erff(v * 0.70710678118654752f));
          outb[(size_t)grow * 1024 + gcol] = __float2bfloat16(ge);
        } else {
          size_t o = (size_t)grow * 256 + gcol;
          outf[o] += v;
        }
      }
    }
  }
}

// ---------------- Sadd precompute: bias+mask in MFMA frag layout ----------------
// Sadd[class][head][frag(mi*4+ni)][lane][j] : q = mi*16+(l>>4)*4+j, key = ni*16+(l&15)
// key >= 49 -> -1e30 (pad exclusion). 4*8*16*64 float4 = 512 KB.
__global__ __launch_bounds__(256) void bias_prep_kernel(
    const float* __restrict__ bt, float* __restrict__ Sadd)
{
  int blk = blockIdx.x;            // class*8 + h
  int cls = blk >> 3, h = blk & 7;
  int re = cls >> 1, ce = cls & 1;
  int lane = threadIdx.x & 63, fs = threadIdx.x >> 6;
  int g = lane >> 4, lm = lane & 15;
  #pragma unroll
  for (int i = 0; i < 4; ++i) {
    int f = fs * 4 + i;
    int mi = f >> 2, ni = f & 3;
    int key = ni * 16 + lm;
    f32x4 v;
    #pragma unroll
    for (int j = 0; j < 4; ++j) {
      int q = mi * 16 + g * 4 + j;
      float val;
      if (key >= 49) {
        val = -1e30f;
      } else {
        int qq = q > 48 ? 48 : q;
        int qh = qq / 7, qw = qq - qh * 7;
        int kh = key / 7, kw = key - kh * 7;
        int rpi = (qh - kh + 6) * 13 + (qw - kw + 6);
        val = bt[rpi * 8 + h];
        int rq = (re ? (qh < 4 ? 1 : 2) : 0) * 3 + (ce ? (qw < 4 ? 1 : 2) : 0);
        int rk = (re ? (kh < 4 ? 1 : 2) : 0) * 3 + (ce ? (kw < 4 ? 1 : 2) : 0);
        if (rq != rk) val -= 100.0f;
      }
      v[j] = val;
    }
    ((f32x4*)Sadd)[(blk * 16 + f) * 64 + lane] = v;
  }
}

// ---------------- MFMA attention: block = (window, 4 heads), wave = head ----------
__global__ __launch_bounds__(256) void attn_mfma_kernel(
    const __hip_bfloat16* __restrict__ qkv,
    const float* __restrict__ Sadd,
    __hip_bfloat16* __restrict__ attn_out)
{
  __shared__ __align__(16) __hip_bfloat16 Pl[4][64 * 72];  // per-wave P, stride 72
  int blk = blockIdx.x;
  int win = blk >> 1, half = blk & 1;
  int w = threadIdx.x >> 6, l = threadIdx.x & 63;
  int head = half * 4 + w;
  int g = l >> 4, lm = l & 15;
  int wi = win & 63;
  int cls = (((wi >> 3) == 7) ? 2 : 0) | (((wi & 7) == 7) ? 1 : 0);
  const __hip_bfloat16* base = qkv + (size_t)win * 49 * 768 + head * 32;

  // ---- S = scale*(Q K^T) + bias + mask ----
  bf16x8 aQ[4], bK[4];
  #pragma unroll
  for (int mi = 0; mi < 4; ++mi) {
    int q = mi * 16 + lm; if (q > 48) q = 48;
    aQ[mi] = *(const bf16x8*)(base + q * 768 + g * 8);
  }
  #pragma unroll
  for (int ni = 0; ni < 4; ++ni) {
    int k = ni * 16 + lm; if (k > 48) k = 48;
    bK[ni] = *(const bf16x8*)(base + 256 + k * 768 + g * 8);
  }
  f32x4 acc[4][4] = {};
  #pragma unroll
  for (int mi = 0; mi < 4; ++mi)
    #pragma unroll
    for (int ni = 0; ni < 4; ++ni)
      acc[mi][ni] = __builtin_amdgcn_mfma_f32_16x16x32_bf16(aQ[mi], bK[ni], acc[mi][ni], 0, 0, 0);

  const float scale = 0.17677669529663687f;  // 1/sqrt(32)
  const f32x4* Sb = (const f32x4*)Sadd + (size_t)(cls * 8 + head) * 16 * 64 + l;

  f32x4 rsum[4];
  __hip_bfloat16* P = Pl[w];
  #pragma unroll
  for (int mi = 0; mi < 4; ++mi) {
    #pragma unroll
    for (int ni = 0; ni < 4; ++ni) {
      f32x4 sv = Sb[(mi * 4 + ni) * 64];
      #pragma unroll
      for (int j = 0; j < 4; ++j) acc[mi][ni][j] = acc[mi][ni][j] * scale + sv[j];
    }
    // row max over keys (cols): per-lane over ni, then butterfly over lane bits 0-3
    f32x4 mx = acc[mi][0];
    #pragma unroll
    for (int ni = 1; ni < 4; ++ni)
      #pragma unroll
      for (int j = 0; j < 4; ++j) mx[j] = fmaxf(mx[j], acc[mi][ni][j]);
    #pragma unroll
    for (int msk = 1; msk < 16; msk <<= 1)
      #pragma unroll
      for (int j = 0; j < 4; ++j) mx[j] = fmaxf(mx[j], __shfl_xor(mx[j], msk));
    f32x4 sm = {};
    #pragma unroll
    for (int ni = 0; ni < 4; ++ni)
      #pragma unroll
      for (int j = 0; j < 4; ++j) {
        float e = __expf(acc[mi][ni][j] - mx[j]);
        acc[mi][ni][j] = e;
        sm[j] += e;
      }
    #pragma unroll
    for (int msk = 1; msk < 16; msk <<= 1)
      #pragma unroll
      for (int j = 0; j < 4; ++j) sm[j] += __shfl_xor(sm[j], msk);
    rsum[mi] = sm;
    // write P rows to LDS [q][key] (stride 72)
    #pragma unroll
    for (int ni = 0; ni < 4; ++ni)
      #pragma unroll
      for (int j = 0; j < 4; ++j) {
        int q = mi * 16 + g * 4 + j;
        int key = ni * 16 + lm;
        P[q * 72 + key] = __float2bfloat16(acc[mi][ni][j]);
      }
  }

  // ---- V B-frags: B(k=key, n=d): lane holds d = n2*16+lm, keys g*8+e (+32s) ----
  bf16x8 bV[2][2];
  #pragma unroll
  for (int s = 0; s < 2; ++s)
    #pragma unroll
    for (int n2 = 0; n2 < 2; ++n2) {
      bf16x8 vv;
      #pragma unroll
      for (int e = 0; e < 8; ++e) {
        int key = s * 32 + g * 8 + e; if (key > 48) key = 48;
        vv[e] = __builtin_bit_cast(short, base[512 + key * 768 + n2 * 16 + lm]);
      }
      bV[s][n2] = vv;
    }

  // ---- O = P @ V ----
  f32x4 o[4][2] = {};
  #pragma unroll
  for (int s = 0; s < 2; ++s)
    #pragma unroll
    for (int mi2 = 0; mi2 < 4; ++mi2) {
      bf16x8 aP = *(const bf16x8*)&P[(mi2 * 16 + lm) * 72 + s * 32 + g * 8];
      #pragma unroll
      for (int n2 = 0; n2 < 2; ++n2)
        o[mi2][n2] = __builtin_amdgcn_mfma_f32_16x16x32_bf16(aP, bV[s][n2], o[mi2][n2], 0, 0, 0);
    }

  // ---- epilogue: normalize rows, store ----
  #pragma unroll
  for (int mi2 = 0; mi2 < 4; ++mi2) {
    f32x4 li;
    #pragma unroll
    for (int j = 0; j < 4; ++j) li[j] = 1.0f / rsum[mi2][j];
    #pragma unroll
    for (int n2 = 0; n2 < 2; ++n2)
      #pragma unroll
      for (int j = 0; j < 4; ++j) {
        int q = mi2 * 16 + g * 4 + j;
        if (q < 49)
          attn_out[((size_t)win * 49 + q) * 256 + head * 32 + n2 * 16 + lm] =
              __float2bfloat16(o[mi2][n2][j] * li[j]);
      }
  }
}

// ---------------- host launch ----------------
extern "C" void kernel_launch(void* const* d_in, const int* in_sizes, int n_in,
                              void* d_out, int out_size, void* d_ws, size_t ws_size,
                              hipStream_t stream) {
  const float* x          = (const float*)d_in[0];
  const float* g1         = (const float*)d_in[1];
  const float* b1         = (const float*)d_in[2];
  const float* qkv_w      = (const float*)d_in[3];
  const float* qkv_b      = (const float*)d_in[4];
  const float* bias_table = (const float*)d_in[5];
  const float* proj_w     = (const float*)d_in[6];
  const float* proj_b     = (const float*)d_in[7];
  const float* g2         = (const float*)d_in[8];
  const float* b2         = (const float*)d_in[9];
  const float* w1         = (const float*)d_in[10];
  const float* bm1        = (const float*)d_in[11];
  const float* w2         = (const float*)d_in[12];
  const float* bm2        = (const float*)d_in[13];
  float* out = (float*)d_out;

  char* ws = (char*)d_ws;
  // layout (bytes):
  //   A_ln   @ 0          : 51,380,224
  //   qkv    @ 51380224   : 154,140,672   (MLP hidden reuses qkv..attn_o)
  //   attn_o @ 205520896  : 51,380,224
  //   weights@ 256901120  : 1,572,864
  //   Sadd   @ 258473984  : 524,288
  __hip_bfloat16* A_ln   = (__hip_bfloat16*)(ws);
  __hip_bfloat16* qkvb   = (__hip_bfloat16*)(ws + 51380224);
  __hip_bfloat16* attn_o = (__hip_bfloat16*)(ws + 205520896);
  __hip_bfloat16* hidden = qkvb;
  __hip_bfloat16* qkv_wb  = (__hip_bfloat16*)(ws + 256901120);
  __hip_bfloat16* proj_wb = qkv_wb + 196608;
  __hip_bfloat16* w1b     = proj_wb + 65536;
  __hip_bfloat16* w2b     = w1b + 262144;
  float* Sadd = (float*)(ws + 258473984);

  cvt_kernel<<<(196608 + 255) / 256, 256, 0, stream>>>(qkv_w, qkv_wb, 196608);
  cvt_kernel<<<(65536  + 255) / 256, 256, 0, stream>>>(proj_w, proj_wb, 65536);
  cvt_kernel<<<(262144 + 255) / 256, 256, 0, stream>>>(w1, w1b, 262144);
  cvt_kernel<<<(262144 + 255) / 256, 256, 0, stream>>>(w2, w2b, 262144);
  bias_prep_kernel<<<32, 256, 0, stream>>>(bias_table, Sadd);

  ln_kernel<true><<<MROWS / 4, 256, 0, stream>>>(x, g1, b1, A_ln);

  gemm_kernel<EPI_QKV><<<(MROWS / BM) * (768 / BN), 256, 0, stream>>>(
      A_ln, qkv_wb, 768, 256, qkv_b, nullptr, nullptr, qkvb);

  attn_mfma_kernel<<<4096, 256, 0, stream>>>(qkvb, Sadd, attn_o);

  gemm_kernel<EPI_PROJ><<<(MROWS / BM) * (256 / BN), 256, 0, stream>>>(
      attn_o, proj_wb, 256, 256, proj_b, x, out, nullptr);

  ln_kernel<false><<<MROWS / 4, 256, 0, stream>>>(out, g2, b2, A_ln);

  gemm_kernel<EPI_MLP1><<<(MROWS / BM) * (1024 / BN), 256, 0, stream>>>(
      A_ln, w1b, 1024, 256, bm1, nullptr, nullptr, hidden);

  gemm_kernel<EPI_MLP2><<<(MROWS / BM) * (256 / BN), 256, 0, stream>>>(
      hidden, w2b, 256, 1024, bm2, nullptr, out, nullptr);
}